// Round 5
// baseline (3513.037 us; speedup 1.0000x reference)
//
#include <hip/hip_runtime.h>
#include <stdint.h>

typedef __bf16 bf16;
typedef __bf16 bf16x8 __attribute__((ext_vector_type(8)));
typedef float  f32x4  __attribute__((ext_vector_type(4)));

#define MFMA16(a, b, c) __builtin_amdgcn_mfma_f32_16x16x32_bf16((a), (b), (c), 0, 0, 0)

static constexpr int    Bn = 4, Tn = 2048, Cn = 2048, HD = 128;
static constexpr size_t TEN = (size_t)Bn * Tn * Cn;   // 16,777,216 elems

__device__ __forceinline__ void gld16(const void* g, void* l) {
  __builtin_amdgcn_global_load_lds(
      (const __attribute__((address_space(1))) void*)g,
      (__attribute__((address_space(3))) void*)l, 16, 0, 0);
}

// ---------------------------------------------------------------------------
// One-shot f32->bf16 for x + all 4 weights. id<8192: x; else weights.
// ---------------------------------------------------------------------------
__global__ __launch_bounds__(256) void convert_all(
    const float* __restrict__ x,  const float* __restrict__ wq,
    const float* __restrict__ wk, const float* __restrict__ wv,
    const float* __restrict__ wp, bf16* __restrict__ xb,
    bf16* __restrict__ wqb, bf16* __restrict__ wkb,
    bf16* __restrict__ wvb, bf16* __restrict__ wpb) {
  const int id = blockIdx.x;
  const float* src; bf16* dst; size_t base;
  if (id < 8192) { src = x; dst = xb; base = (size_t)id * 2048; }
  else {
    const int t = id - 8192, w = t >> 11, j = t & 2047;
    src = (w == 0) ? wq : (w == 1) ? wk : (w == 2) ? wv : wp;
    dst = (w == 0) ? wqb : (w == 1) ? wkb : (w == 2) ? wvb : wpb;
    base = (size_t)j * 2048;
  }
  const size_t i = base + (size_t)threadIdx.x * 8;
  float4 a = *(const float4*)(src + i);
  float4 b = *(const float4*)(src + i + 4);
  bf16x8 o = {(bf16)a.x, (bf16)a.y, (bf16)a.z, (bf16)a.w,
              (bf16)b.x, (bf16)b.y, (bf16)b.z, (bf16)b.w};
  *(bf16x8*)(dst + i) = o;
}

// ---------------------------------------------------------------------------
// GEMM core (m97): 128x128 tile, BK=32, global_load_lds width-16.
// rope_sel: -1 none, 0 q (rope + scale*log2e), 1 k (rope only).
// ---------------------------------------------------------------------------
template <bool OUT_F32>
__device__ __forceinline__ void gemm_body(const bf16* __restrict__ A,
                                          const bf16* __restrict__ Bt,
                                          void* __restrict__ Cv,
                                          int m0, int n0, int N, int K,
                                          int rope_sel) {
  __shared__ bf16 sA[128 * 32];
  __shared__ bf16 sB[128 * 32];
  const int tid  = threadIdx.x;
  const int lane = tid & 63, wid = tid >> 6;
  const int quad = lane >> 4, l16 = lane & 15;
  const int wm = (wid & 1) * 64, wn = (wid >> 1) * 64;

  f32x4 acc[4][4] = {};

  const int e0 = tid * 8;
  const int r0 = e0 >> 5, c0 = e0 & 31;
  const bf16* gA = A + (size_t)(m0 + r0) * K + c0;
  const bf16* gB = Bt + (size_t)(n0 + r0) * K + c0;

  for (int k0 = 0; k0 < K; k0 += 32) {
    gld16(gA,                  &sA[e0]);
    gld16(gA + (size_t)64 * K, &sA[e0 + 2048]);
    gld16(gB,                  &sB[e0]);
    gld16(gB + (size_t)64 * K, &sB[e0 + 2048]);
    gA += 32; gB += 32;
    __syncthreads();

    bf16x8 af[4], bfr[4];
#pragma unroll
    for (int i = 0; i < 4; i++) {
      af[i]  = *(const bf16x8*)&sA[(wm + i * 16 + l16) * 32 + quad * 8];
      bfr[i] = *(const bf16x8*)&sB[(wn + i * 16 + l16) * 32 + quad * 8];
    }
#pragma unroll
    for (int im = 0; im < 4; im++)
#pragma unroll
      for (int in = 0; in < 4; in++)
        acc[im][in] = MFMA16(af[im], bfr[in], acc[im][in]);
    __syncthreads();
  }

  if (rope_sel >= 0) {
    // fused RoPE: pair = adjacent cols (lane l16 ^ 1), angle = t*10000^(-i/64)
    const float qm = (rope_sel == 0)
        ? (0.08838834764831845f * 1.4426950408889634f) : 1.0f;
    float fi[4];
#pragma unroll
    for (int in = 0; in < 4; in++) {
      int col = n0 + wn + in * 16 + l16;
      fi[in] = __expf(-(float)((col & 127) >> 1) * 0.14391156831212787f);
    }
#pragma unroll
    for (int im = 0; im < 4; im++)
#pragma unroll
      for (int r = 0; r < 4; r++) {
        const int row = m0 + wm + im * 16 + quad * 4 + r;
        const float t = (float)(row & (Tn - 1));
#pragma unroll
        for (int in = 0; in < 4; in++) {
          const float val = acc[im][in][r];
          const float partner = __shfl_xor(val, 1);
          float sn, cs;
          sincosf(t * fi[in], &sn, &cs);
          const float o = (l16 & 1) ? (partner * sn + val * cs)
                                    : (val * cs - partner * sn);
          const int col = n0 + wn + in * 16 + l16;
          ((bf16*)Cv)[(size_t)row * N + col] = (bf16)(o * qm);
        }
      }
  } else {
#pragma unroll
    for (int im = 0; im < 4; im++)
#pragma unroll
      for (int in = 0; in < 4; in++)
#pragma unroll
        for (int r = 0; r < 4; r++) {
          int row = m0 + wm + im * 16 + quad * 4 + r;
          int col = n0 + wn + in * 16 + l16;
          if (OUT_F32)
            ((float*)Cv)[(size_t)row * N + col] = acc[im][in][r];
          else
            ((bf16*)Cv)[(size_t)row * N + col] = (bf16)acc[im][in][r];
        }
  }
}

__global__ __launch_bounds__(256) void qkv_gemm(const bf16* __restrict__ X,
                                                const bf16* __restrict__ Wq,
                                                const bf16* __restrict__ Wk,
                                                const bf16* __restrict__ Wv,
                                                bf16* __restrict__ qkv) {
  const int sel = blockIdx.x >> 4;
  const bf16* Bt = (sel == 0) ? Wq : (sel == 1) ? Wk : Wv;
  bf16* out = qkv + (size_t)sel * TEN;
  const int rope_sel = (sel < 2) ? sel : -1;
  gemm_body<false>(X, Bt, out, blockIdx.y * 128, (blockIdx.x & 15) * 128,
                   Cn, Cn, rope_sel);
}

__global__ __launch_bounds__(256) void out_gemm(const bf16* __restrict__ Y,
                                                const bf16* __restrict__ Wp,
                                                float* __restrict__ O) {
  gemm_body<true>(Y, Wp, O, blockIdx.y * 128, blockIdx.x * 128, Cn, Cn, -1);
}

// ---------------------------------------------------------------------------
// V transpose: v (B*T, C) -> vt (B, C, T), 64x64 tiles, LDS stride 65.
// ---------------------------------------------------------------------------
__global__ __launch_bounds__(256) void transpose_v(const bf16* __restrict__ v,
                                                   bf16* __restrict__ vt) {
  __shared__ bf16 tile[64 * 65];
  const int tid = threadIdx.x;
  const int t0 = blockIdx.x * 64, c0 = blockIdx.y * 64, b = blockIdx.z;
  const bf16* src = v + ((size_t)(b * Tn + t0)) * Cn + c0;
  bf16* dst = vt + ((size_t)(b * Cn + c0)) * Tn + t0;
#pragma unroll
  for (int i = 0; i < 16; i++) {
    int lin = i * 256 + tid;
    int r = lin >> 6, c = lin & 63;
    tile[r * 65 + c] = src[(size_t)r * Cn + c];
  }
  __syncthreads();
#pragma unroll
  for (int i = 0; i < 16; i++) {
    int lin = i * 256 + tid;
    int cc = lin >> 6, t = lin & 63;
    dst[(size_t)cc * Tn + t] = tile[t * 65 + cc];
  }
}

// ---------------------------------------------------------------------------
// Causal flash attention with register-prefetch pipeline.
// Block = 128 q-rows of one (b,h); wave w owns rows [w*32, w*32+32).
// q arrives pre-scaled by softmax_scale*log2e (exp2 online softmax).
// sP uses an XOR col-group swizzle (conflict-free scatter writes).
// ---------------------------------------------------------------------------
__global__ __launch_bounds__(256, 2) void attn(const bf16* __restrict__ q,
                                               const bf16* __restrict__ k,
                                               const bf16* __restrict__ vt,
                                               bf16* __restrict__ y) {
  __shared__ bf16 sK[64 * 136];    // K tile (64 keys x 128 d)
  __shared__ bf16 sVt[128 * 72];   // V^T tile (128 d x 64 keys)
  __shared__ bf16 sP[128 * 72];    // P tile (128 q x 64 keys), swizzled

  const int tid = threadIdx.x;
  const int bh = blockIdx.x;
  const int qt = 15 - blockIdx.y;          // heavy blocks dispatched first
  const int b = bh >> 4, h = bh & 15;
  const int q0 = qt * 128;
  const int lane = tid & 63, w = tid >> 6;
  const int quad = lane >> 4, l16 = lane & 15;

  const bf16* qbase  = q + ((size_t)(b * Tn + q0)) * Cn + h * HD;
  const bf16* kbase  = k + ((size_t)(b * Tn)) * Cn + h * HD;
  const bf16* vtbase = vt + ((size_t)(b * Cn + h * HD)) * Tn;

  // staging geometry (per thread, 4 chunks each)
  const int krow = tid >> 4,        kcol = (tid & 15) * 8;   // +16 rows/iter
  const int vrow = tid >> 3,        vcol = (tid & 7) * 8;    // +32 rows/iter

  // Q fragments direct from global (one-time)
  bf16x8 qf[2][4];
#pragma unroll
  for (int im = 0; im < 2; im++)
#pragma unroll
    for (int s = 0; s < 4; s++)
      qf[im][s] = *(const bf16x8*)(qbase +
          (size_t)(w * 32 + im * 16 + l16) * Cn + s * 32 + quad * 8);

  f32x4 O[2][8] = {};
  float mrow[2][4], lrow[2][4];
#pragma unroll
  for (int im = 0; im < 2; im++)
#pragma unroll
    for (int r = 0; r < 4; r++) { mrow[im][r] = -1e30f; lrow[im][r] = 0.f; }

  uint4 kreg[4], vreg[4];
#pragma unroll
  for (int i = 0; i < 4; i++) {
    kreg[i] = *(const uint4*)(kbase + (size_t)(krow + i * 16) * Cn + kcol);
    vreg[i] = *(const uint4*)(vtbase + (size_t)(vrow + i * 32) * Tn + vcol);
  }
#pragma unroll
  for (int i = 0; i < 4; i++) {
    *(uint4*)&sK[(krow + i * 16) * 136 + kcol] = kreg[i];
    *(uint4*)&sVt[(vrow + i * 32) * 72 + vcol] = vreg[i];
  }
  __syncthreads();

  const int nkt = 2 * qt + 2;
  const int swr = (l16 >> 2) & 3;          // pf-read swizzle term
  for (int kt = 0; kt < nkt; kt++) {
    if (kt + 1 < nkt) {                    // prefetch next K/V tile into regs
      const bf16* kb = kbase + (size_t)(kt + 1) * 64 * Cn;
      const bf16* vb = vtbase + (size_t)(kt + 1) * 64;
#pragma unroll
      for (int i = 0; i < 4; i++) {
        kreg[i] = *(const uint4*)(kb + (size_t)(krow + i * 16) * Cn + kcol);
        vreg[i] = *(const uint4*)(vb + (size_t)(vrow + i * 32) * Tn + vcol);
      }
    }

    // wave-uniform skip of fully-future tiles
    if (kt * 64 <= q0 + w * 32 + 31) {
      f32x4 sv[2][4] = {};
#pragma unroll
      for (int s = 0; s < 4; s++)
#pragma unroll
        for (int jn = 0; jn < 4; jn++) {
          bf16x8 kf = *(const bf16x8*)&sK[(jn * 16 + l16) * 136 + s * 32 + quad * 8];
          sv[0][jn] = MFMA16(qf[0][s], kf, sv[0][jn]);
          sv[1][jn] = MFMA16(qf[1][s], kf, sv[1][jn]);
        }

      const bool anymask = (kt >= 2 * qt);
#pragma unroll
      for (int im = 0; im < 2; im++)
#pragma unroll
        for (int r = 0; r < 4; r++) {
          float pv[4];
          float mx = -1e30f;
#pragma unroll
          for (int jn = 0; jn < 4; jn++) {
            float x = sv[im][jn][r];
            if (anymask) {
              int key = kt * 64 + jn * 16 + l16;
              int qr  = q0 + w * 32 + im * 16 + quad * 4 + r;
              if (key > qr) x = -1e30f;
            }
            pv[jn] = x;
            mx = fmaxf(mx, x);
          }
          mx = fmaxf(mx, __shfl_xor(mx, 1));
          mx = fmaxf(mx, __shfl_xor(mx, 2));
          mx = fmaxf(mx, __shfl_xor(mx, 4));
          mx = fmaxf(mx, __shfl_xor(mx, 8));
          const float mn = fmaxf(mrow[im][r], mx);
          const float alpha = exp2f(mrow[im][r] - mn);
          mrow[im][r] = mn;
          float rs = 0.f;
          const int prow = (w * 32 + im * 16 + quad * 4 + r) * 72;
#pragma unroll
          for (int jn = 0; jn < 4; jn++) {
            float e = exp2f(pv[jn] - mn);
            // swizzled store: col_group (2jn + l16>>3) ^ quad
            sP[prow + (((2 * jn + (l16 >> 3)) ^ quad) * 8) + (l16 & 7)] = (bf16)e;
            rs += e;
          }
          rs += __shfl_xor(rs, 1);
          rs += __shfl_xor(rs, 2);
          rs += __shfl_xor(rs, 4);
          rs += __shfl_xor(rs, 8);
          lrow[im][r] = lrow[im][r] * alpha + rs;
#pragma unroll
          for (int n = 0; n < 8; n++) O[im][n][r] *= alpha;
        }

#pragma unroll
      for (int s2 = 0; s2 < 2; s2++) {
        const int pg = ((4 * s2 + quad) ^ swr) * 8;
        bf16x8 pf0 = *(const bf16x8*)&sP[(w * 32 + l16) * 72 + pg];
        bf16x8 pf1 = *(const bf16x8*)&sP[(w * 32 + 16 + l16) * 72 + pg];
#pragma unroll
        for (int n = 0; n < 8; n++) {
          bf16x8 vf = *(const bf16x8*)&sVt[(n * 16 + l16) * 72 + s2 * 32 + quad * 8];
          O[0][n] = MFMA16(pf0, vf, O[0][n]);
          O[1][n] = MFMA16(pf1, vf, O[1][n]);
        }
      }
    }
    __syncthreads();                       // everyone done reading sK/sVt
    if (kt + 1 < nkt) {
#pragma unroll
      for (int i = 0; i < 4; i++) {        // regs -> LDS (waits vmcnt here)
        *(uint4*)&sK[(krow + i * 16) * 136 + kcol] = kreg[i];
        *(uint4*)&sVt[(vrow + i * 32) * 72 + vcol] = vreg[i];
      }
    }
    __syncthreads();
  }

#pragma unroll
  for (int im = 0; im < 2; im++) {
    bf16* ybase = y + ((size_t)(b * Tn + q0 + w * 32 + im * 16)) * Cn + h * HD;
#pragma unroll
    for (int r = 0; r < 4; r++) {
      const float inv = 1.f / lrow[im][r];
#pragma unroll
      for (int n = 0; n < 8; n++)
        ybase[(size_t)(quad * 4 + r) * Cn + n * 16 + l16] = (bf16)(O[im][n][r] * inv);
    }
  }
}

// ---------------------------------------------------------------------------
extern "C" void kernel_launch(void* const* d_in, const int* in_sizes, int n_in,
                              void* d_out, int out_size, void* d_ws, size_t ws_size,
                              hipStream_t stream) {
  (void)in_sizes; (void)n_in; (void)out_size; (void)ws_size;
  const float* x  = (const float*)d_in[0];
  const float* Wq = (const float*)d_in[1];
  const float* Wk = (const float*)d_in[2];
  const float* Wv = (const float*)d_in[3];
  const float* Wp = (const float*)d_in[4];
  float* out = (float*)d_out;
  bf16*  ws  = (bf16*)d_ws;

  bf16* q   = ws;                    // (B*T, C)
  bf16* kk  = ws + TEN;              // (B*T, C)
  bf16* v   = ws + 2 * TEN;          // (B*T, C)
  bf16* vt  = ws + 3 * TEN;          // (B, C, T)
  bf16* wqb = ws + 3 * TEN;          // alias vt (dead after qkv_gemm)
  bf16* wkb = ws + 3 * TEN + TEN / 4;
  bf16* wvb = ws + 3 * TEN + TEN / 2;
  bf16* xb  = ws + 4 * TEN;          // alias y (dead after qkv_gemm)
  bf16* y   = ws + 4 * TEN;
  bf16* wpb = ws + 5 * TEN;

  convert_all<<<dim3(16384), 256, 0, stream>>>(x, Wq, Wk, Wv, Wp,
                                               xb, wqb, wkb, wvb, wpb);
  qkv_gemm   <<<dim3(48, 64), 256, 0, stream>>>(xb, wqb, wkb, wvb, ws);
  transpose_v<<<dim3(32, 32, 4), 256, 0, stream>>>(v, vt);
  attn       <<<dim3(64, 16), 256, 0, stream>>>(q, kk, vt, y);
  out_gemm   <<<dim3(16, 64), 256, 0, stream>>>(y, wpb, out);
}